// Round 2
// baseline (2424.931 us; speedup 1.0000x reference)
//
#include <hip/hip_runtime.h>

#define BB 64
#define TT 2048
#define II 64
#define HH 256

// tanh(x) = 1 - 2/(e^{2x}+1); v_exp + v_rcp, correct limits at +-inf.
__device__ __forceinline__ float ftanh(float x) {
    float e = __expf(2.0f * x);
    return 1.0f - 2.0f * __builtin_amdgcn_rcpf(e + 1.0f);
}

// butterfly add with lane^1 / lane^2 via DPP quad_perm (VALU pipe, no LDS)
template <int CTRL>
__device__ __forceinline__ float dpp_xor_add(float v) {
    int s = __builtin_amdgcn_update_dpp(0, __float_as_int(v), CTRL, 0xF, 0xF, true);
    return v + __int_as_float(s);
}
// butterfly add with lane^4 via ds_swizzle (xor=4, and=0x1F)
__device__ __forceinline__ float swz_xor4_add(float v) {
    int s = __builtin_amdgcn_ds_swizzle(__float_as_int(v), 0x101F);
    return v + __int_as_float(s);
}

__launch_bounds__(512, 2)
__global__ void rnn_fused(const float* __restrict__ x,
                          const float* __restrict__ W_ih,
                          const float* __restrict__ W_hh,
                          const float* __restrict__ b_ih,
                          const float* __restrict__ b_hh,
                          const float* __restrict__ W_fc,
                          const float* __restrict__ b_fc,
                          float* __restrict__ out) {
    // h double-buffered, padded stride 36 floats per 32-value group:
    // addr(t) = (t>>5)*36 + (t&31). Slice q reads [q*36, q*36+32) -> 8 distinct
    // bank-quads across q for each b128 -> conflict-free broadcast.
    __shared__ __align__(16) float hbuf[2][288];
    __shared__ __align__(16) float xbuf[2][64];
    __shared__ float wavepart[2][8];

    const int tid  = threadIdx.x;
    const int b    = blockIdx.x;
    const int lane = tid & 63;
    const int w    = tid >> 6;   // wave 0..7
    const int o    = lane >> 3;  // output sub-slot 0..7
    const int q    = lane & 7;   // k-slice 0..7 (low bits -> DPP-friendly)

    // ---- persistent weights in VGPRs ----
    // thread owns rows t_r = w*32 + r*8 + o (r=0..3), cols [q*32, q*32+32)
    float4 whh4[4][8];   // 128 VGPRs
    float4 wih4[4][2];   // 32 VGPRs, cols [q*8, q*8+8) of W_ih
    float  bias[4];
#pragma unroll
    for (int r = 0; r < 4; ++r) {
        const int t_r = w * 32 + r * 8 + o;
        const float4* wr = (const float4*)(W_hh + t_r * HH + q * 32);
#pragma unroll
        for (int jv = 0; jv < 8; ++jv) whh4[r][jv] = wr[jv];
        const float4* wi = (const float4*)(W_ih + t_r * II + q * 8);
        wih4[r][0] = wi[0];
        wih4[r][1] = wi[1];
        bias[r] = b_ih[t_r] + b_hh[t_r];
    }
    const float wfc = (tid < HH) ? W_fc[tid] : 0.0f;
    const float bfc = b_fc[0];

    // ---- init LDS: h0 = 0, stage x row 0 ----
    for (int idx = tid; idx < 2 * 288; idx += 512) ((float*)hbuf)[idx] = 0.0f;
    const float4* x4 = (const float4*)x;
    if (tid < 16) ((float4*)&xbuf[0][0])[tid] = x4[(size_t)(b * TT) * 16 + tid];
    __syncthreads();

    int p = 0;
    for (int i = 0; i < TT; ++i) {
        // prefetch x row i+1 into registers (consumed at end of this iter)
        float4 xpre;
        if (tid < 16) {
            const int row = (i + 1 < TT) ? (i + 1) : (TT - 1);
            xpre = x4[(size_t)(b * TT + row) * 16 + tid];
        }

        // ---- K-loop: partial dot over this thread's 32-col slice ----
        float acc[4] = {0.0f, 0.0f, 0.0f, 0.0f};
        const float4* hp = (const float4*)&hbuf[p][0];
#pragma unroll
        for (int jv = 0; jv < 8; ++jv) {
            const float4 h4 = hp[q * 9 + jv];
#pragma unroll
            for (int r = 0; r < 4; ++r) {
                acc[r] = fmaf(whh4[r][jv].x, h4.x, acc[r]);
                acc[r] = fmaf(whh4[r][jv].y, h4.y, acc[r]);
                acc[r] = fmaf(whh4[r][jv].z, h4.z, acc[r]);
                acc[r] = fmaf(whh4[r][jv].w, h4.w, acc[r]);
            }
        }
        // fused input projection: x[b][i][q*8 .. q*8+8)
        {
            const float4* xp = (const float4*)&xbuf[p][q * 8];
            const float4 xa = xp[0], xb = xp[1];
#pragma unroll
            for (int r = 0; r < 4; ++r) {
                acc[r] = fmaf(wih4[r][0].x, xa.x, acc[r]);
                acc[r] = fmaf(wih4[r][0].y, xa.y, acc[r]);
                acc[r] = fmaf(wih4[r][0].z, xa.z, acc[r]);
                acc[r] = fmaf(wih4[r][0].w, xa.w, acc[r]);
                acc[r] = fmaf(wih4[r][1].x, xb.x, acc[r]);
                acc[r] = fmaf(wih4[r][1].y, xb.y, acc[r]);
                acc[r] = fmaf(wih4[r][1].z, xb.z, acc[r]);
                acc[r] = fmaf(wih4[r][1].w, xb.w, acc[r]);
            }
        }
        // ---- reduce over the 8 k-slices (lane bits 0..2) ----
#pragma unroll
        for (int r = 0; r < 4; ++r) {
            acc[r] = dpp_xor_add<0xB1>(acc[r]);  // xor 1 (quad_perm 1,0,3,2)
            acc[r] = dpp_xor_add<0x4E>(acc[r]);  // xor 2 (quad_perm 2,3,0,1)
            acc[r] = swz_xor4_add(acc[r]);       // xor 4
        }

        const int pn = p ^ 1;
        if (q == 0) {
#pragma unroll
            for (int r = 0; r < 4; ++r) {
                const float hn = ftanh(acc[r] + bias[r]);
                hbuf[pn][w * 36 + r * 8 + o] = hn;
            }
        }
        __syncthreads();  // h_{i+1} visible

        // ---- fused output head: out[b][i] = dot(h_{i+1}, W_fc) + b_fc ----
        if (tid < HH) {
            const float hv = hbuf[pn][(tid >> 5) * 36 + (tid & 31)];
            float c = hv * wfc;
#pragma unroll
            for (int off = 32; off >= 1; off >>= 1) c += __shfl_xor(c, off, 64);
            if (lane == 0) wavepart[pn][tid >> 6] = c;
        }
        // store previous step's result (its waveparts are fence-safe by now)
        if (tid == 0 && i > 0) {
            out[(size_t)b * TT + (i - 1)] =
                wavepart[p][0] + wavepart[p][1] + wavepart[p][2] + wavepart[p][3] + bfc;
        }
        if (tid < 16) ((float4*)&xbuf[pn][0])[tid] = xpre;
        __syncthreads();  // waveparts + x row visible for next iter
        p = pn;
    }
    if (tid == 0) {
        out[(size_t)b * TT + (TT - 1)] =
            wavepart[p][0] + wavepart[p][1] + wavepart[p][2] + wavepart[p][3] + bfc;
    }
}

extern "C" void kernel_launch(void* const* d_in, const int* in_sizes, int n_in,
                              void* d_out, int out_size, void* d_ws, size_t ws_size,
                              hipStream_t stream) {
    const float* x    = (const float*)d_in[0];
    const float* W_ih = (const float*)d_in[1];
    const float* W_hh = (const float*)d_in[2];
    const float* b_ih = (const float*)d_in[3];
    const float* b_hh = (const float*)d_in[4];
    const float* W_fc = (const float*)d_in[5];
    const float* b_fc = (const float*)d_in[6];
    float* out = (float*)d_out;

    rnn_fused<<<BB, 512, 0, stream>>>(x, W_ih, W_hh, b_ih, b_hh, W_fc, b_fc, out);
}

// Round 3
// 1601.837 us; speedup vs baseline: 1.5138x; 1.5138x over previous
//
#include <hip/hip_runtime.h>

#define BB 64
#define TT 2048
#define II 64
#define HH 256

// tanh(x) = 1 - 2/(e^{2x}+1); v_exp + v_rcp, correct limits at +-inf.
__device__ __forceinline__ float ftanh(float x) {
    float e = __expf(2.0f * x);
    return 1.0f - 2.0f * __builtin_amdgcn_rcpf(e + 1.0f);
}

// add partner value via DPP (VALU pipe). Requires compile-time ctrl.
// 0xB1 = quad_perm(1,0,3,2) = xor1 ; 0x4E = quad_perm(2,3,0,1) = xor2
// 0x141 = ROW_HALF_MIRROR (lane^7; == xor4 once bits0-1 are orbit-uniform)
// 0x140 = ROW_MIRROR      (lane^15; == xor8 once bits0-2 are orbit-uniform)
template <int CTRL>
__device__ __forceinline__ float dpp_add(float v) {
    int s = __builtin_amdgcn_update_dpp(0, __float_as_int(v), CTRL, 0xF, 0xF, true);
    return v + __int_as_float(s);
}
// ds_swizzle xor-add (within 32-lane halves). 0x401F = xor16.
template <int PAT>
__device__ __forceinline__ float swz_add(float v) {
    int s = __builtin_amdgcn_ds_swizzle(__float_as_int(v), PAT);
    return v + __int_as_float(s);
}

// block = 1024 threads (16 waves, 4/SIMD); min 4 waves/EU forces VGPR<=128 so
// the per-thread weight tile (2x8 float4 whh + 2x2 float4 wih ~= 84 regs) stays
// in architectural VGPRs (R2's 512-thr/4-row variant got split to AGPRs at 104).
__launch_bounds__(1024, 4)
__global__ void rnn_fused(const float* __restrict__ x,
                          const float* __restrict__ W_ih,
                          const float* __restrict__ W_hh,
                          const float* __restrict__ b_ih,
                          const float* __restrict__ b_hh,
                          const float* __restrict__ W_fc,
                          const float* __restrict__ b_fc,
                          float* __restrict__ out) {
    // h double-buffered; padded stride 36 per 32-value group:
    // addr(t) = (t>>5)*36 + (t&31) -> the 8 q-slices hit disjoint bank quads.
    __shared__ __align__(16) float hbuf[2][288];
    __shared__ float wavepart[2][32];

    const int tid  = threadIdx.x;
    const int b    = blockIdx.x;
    const int lane = tid & 63;
    const int w    = tid >> 6;   // wave 0..15
    const int o    = lane >> 3;  // row sub-slot 0..7
    const int q    = lane & 7;   // k-slice 0..7 (lane bits 0..2)

    // thread owns rows t_r = w*16 + r*8 + o (r=0,1), cols [q*32, q*32+32)
    float4 whh4[2][8];   // 64 VGPRs
    float4 wih4[2][2];   // 16 VGPRs
    float  bias[2], wfcr[2];
#pragma unroll
    for (int r = 0; r < 2; ++r) {
        const int t_r = w * 16 + r * 8 + o;
        const float4* wr = (const float4*)(W_hh + t_r * HH + q * 32);
#pragma unroll
        for (int jv = 0; jv < 8; ++jv) whh4[r][jv] = wr[jv];
        const float4* wi = (const float4*)(W_ih + t_r * II + q * 8);
        wih4[r][0] = wi[0];
        wih4[r][1] = wi[1];
        bias[r] = b_ih[t_r] + b_hh[t_r];
        wfcr[r] = W_fc[t_r];
    }
    const float bfc = b_fc[0];

    for (int idx = tid; idx < 2 * 288; idx += 1024) ((float*)hbuf)[idx] = 0.0f;
    __syncthreads();

    const float* xbase = x + (size_t)b * TT * II + q * 8;
    float* outb = out + (size_t)b * TT;

    int p = 0;
    for (int i = 0; i < TT; ++i) {
        // x slice straight from global (L1 broadcast across the 128 threads
        // sharing q); issued at loop top, consumed after the recurrent FMAs.
        const float4* xp = (const float4*)(xbase + i * II);
        const float4 xa = xp[0];
        const float4 xc = xp[1];

        float acc0 = 0.0f, acc1 = 0.0f;
        const float4* hp = (const float4*)(&hbuf[p][0]) + q * 9;
#pragma unroll
        for (int jv = 0; jv < 8; ++jv) {
            const float4 h4 = hp[jv];
            acc0 = fmaf(whh4[0][jv].x, h4.x, acc0);
            acc0 = fmaf(whh4[0][jv].y, h4.y, acc0);
            acc0 = fmaf(whh4[0][jv].z, h4.z, acc0);
            acc0 = fmaf(whh4[0][jv].w, h4.w, acc0);
            acc1 = fmaf(whh4[1][jv].x, h4.x, acc1);
            acc1 = fmaf(whh4[1][jv].y, h4.y, acc1);
            acc1 = fmaf(whh4[1][jv].z, h4.z, acc1);
            acc1 = fmaf(whh4[1][jv].w, h4.w, acc1);
        }
        // fused input projection: x[b][i][q*8 .. q*8+8)
        acc0 = fmaf(wih4[0][0].x, xa.x, acc0);
        acc0 = fmaf(wih4[0][0].y, xa.y, acc0);
        acc0 = fmaf(wih4[0][0].z, xa.z, acc0);
        acc0 = fmaf(wih4[0][0].w, xa.w, acc0);
        acc0 = fmaf(wih4[0][1].x, xc.x, acc0);
        acc0 = fmaf(wih4[0][1].y, xc.y, acc0);
        acc0 = fmaf(wih4[0][1].z, xc.z, acc0);
        acc0 = fmaf(wih4[0][1].w, xc.w, acc0);
        acc1 = fmaf(wih4[1][0].x, xa.x, acc1);
        acc1 = fmaf(wih4[1][0].y, xa.y, acc1);
        acc1 = fmaf(wih4[1][0].z, xa.z, acc1);
        acc1 = fmaf(wih4[1][0].w, xa.w, acc1);
        acc1 = fmaf(wih4[1][1].x, xc.x, acc1);
        acc1 = fmaf(wih4[1][1].y, xc.y, acc1);
        acc1 = fmaf(wih4[1][1].z, xc.z, acc1);
        acc1 = fmaf(wih4[1][1].w, xc.w, acc1);

        // all-reduce over the 8 k-slices (lane bits 0..2) — pure DPP
        acc0 = dpp_add<0xB1>(acc0);
        acc0 = dpp_add<0x4E>(acc0);
        acc0 = dpp_add<0x141>(acc0);
        acc1 = dpp_add<0xB1>(acc1);
        acc1 = dpp_add<0x4E>(acc1);
        acc1 = dpp_add<0x141>(acc1);

        // every lane now holds the full row sums -> compute tanh uniformly
        const float h0 = ftanh(acc0 + bias[0]);
        const float h1 = ftanh(acc1 + bias[1]);

        const int pn = p ^ 1;
        if (q == 0) {
            const int t0 = w * 16 + o;
            const int t1 = t0 + 8;
            hbuf[pn][(t0 >> 5) * 36 + (t0 & 31)] = h0;
            hbuf[pn][(t1 >> 5) * 36 + (t1 & 31)] = h1;
        }

        // output head partial: c(w,o) = h0*wfc[t0] + h1*wfc[t1]; reduce over o
        float c = fmaf(h1, wfcr[1], h0 * wfcr[0]);
        c = dpp_add<0x140>(c);    // xor8  (bits0-2 uniform -> row_mirror ok)
        c = swz_add<0x401F>(c);   // xor16
        if ((lane & 31) == 0) wavepart[pn][w * 2 + (lane >> 5)] = c;

        __syncthreads();  // h_{i+1} + waveparts visible; ONE barrier per step

        // previous step's scalar output: wave 0 sums the 32 partials (all-DPP)
        if (w == 0 && i > 0) {
            float s2 = wavepart[p][lane & 31];
            s2 = dpp_add<0xB1>(s2);
            s2 = dpp_add<0x4E>(s2);
            s2 = dpp_add<0x141>(s2);
            s2 = dpp_add<0x140>(s2);
            s2 = swz_add<0x401F>(s2);
            if (lane == 0) outb[i - 1] = s2 + bfc;
        }
        p = pn;
    }
    __syncthreads();
    if (w == 0) {
        float s2 = wavepart[p][lane & 31];
        s2 = dpp_add<0xB1>(s2);
        s2 = dpp_add<0x4E>(s2);
        s2 = dpp_add<0x141>(s2);
        s2 = dpp_add<0x140>(s2);
        s2 = swz_add<0x401F>(s2);
        if (lane == 0) outb[TT - 1] = s2 + bfc;
    }
}

extern "C" void kernel_launch(void* const* d_in, const int* in_sizes, int n_in,
                              void* d_out, int out_size, void* d_ws, size_t ws_size,
                              hipStream_t stream) {
    const float* x    = (const float*)d_in[0];
    const float* W_ih = (const float*)d_in[1];
    const float* W_hh = (const float*)d_in[2];
    const float* b_ih = (const float*)d_in[3];
    const float* b_hh = (const float*)d_in[4];
    const float* W_fc = (const float*)d_in[5];
    const float* b_fc = (const float*)d_in[6];
    float* out = (float*)d_out;

    rnn_fused<<<BB, 1024, 0, stream>>>(x, W_ih, W_hh, b_ih, b_hh, W_fc, b_fc, out);
}